// Round 9
// baseline (165.239 us; speedup 1.0000x reference)
//
#include <hip/hip_runtime.h>
#include <math.h>

// Fused ConvTranspose2d(64->64,k4,s2,p1) + BN + softmax(C) + maxpool2x2 via bf16 MFMA.
//
// Parity classes (r,p) of (oh,ow): 4 independent GEMMs sharing m=(n,ph,pw);
// maxpool = register max across class results. MFMA 16x16x32 bf16, K=256 (4 taps x 64 cin).
//
// R8b: M=64 per wave (wave = one pooled row, 4 m-tiles; block = 4 rows) -> weight
//     L2 traffic halves to 256 MB and each bfrag feeds 16 MFMAs (covers L2 latency).
//     Register diet: BN folded into weights, exp in place, pooled packed as
//     _Float16 x2 (explicit elementwise max -> v_pk_max_f16; __hmax2 is broken
//     in ROCm 7.2 headers). ~110 VGPR + 64 AGPR, no spill.
//     Staging: lane<->column, 8 strided dword loads -> 1 swizzled b128 LDS write.

typedef __attribute__((ext_vector_type(8))) short short8;
typedef __attribute__((ext_vector_type(4))) float floatx4;
typedef _Float16 __attribute__((ext_vector_type(2))) h2;

#define COLS 66

__device__ ushort g_wfrag[4 * 8 * 4 * 64 * 8];  // [class][ks][nt][lane][j], 128 KB
__device__ float g_aff[64];  // D = (bias-mean)*A+beta  (A folded into weights)

__device__ __forceinline__ ushort f2bf(float f) {
  union { float f; unsigned u; } v; v.f = f;
  unsigned r = v.u + 0x7FFF + ((v.u >> 16) & 1);  // RNE
  return (ushort)(r >> 16);
}

__device__ __forceinline__ h2 h2max(h2 a, h2 b) {
  h2 r;
  r.x = (a.x > b.x) ? a.x : b.x;
  r.y = (a.y > b.y) ? a.y : b.y;
  return r;
}

// prep: thread = (cin pair, cout). BN scale A[cout] folded into weights here.
__global__ __launch_bounds__(256) void prep_kernel(
    const float* __restrict__ w, const float* __restrict__ bias,
    const float* __restrict__ gamma, const float* __restrict__ beta,
    const float* __restrict__ mean, const float* __restrict__ var) {
  int t = blockIdx.x * 256 + threadIdx.x;  // 0..2047
  int cin0 = (t >> 6) * 2;                 // even cin
  int cout = t & 63;
  int nt = cout >> 4, b15 = cout & 15;
  int q = (cin0 & 31) >> 3;                // quad within k-step
  int j = cin0 & 7;                        // j within quad (even)
  int ksq = cin0 >> 5;                     // which 32-block within tap
  float A = gamma[cout] * rsqrtf(var[cout] + 1e-5f);

  const float4* p0 = (const float4*)&w[(cin0 * 64 + cout) * 16];
  const float4* p1 = (const float4*)&w[((cin0 + 1) * 64 + cout) * 16];
  float a[16], b[16];
  {
    float4 f0 = p0[0], f1 = p0[1], f2 = p0[2], f3 = p0[3];
    a[0]=f0.x; a[1]=f0.y; a[2]=f0.z; a[3]=f0.w; a[4]=f1.x; a[5]=f1.y; a[6]=f1.z; a[7]=f1.w;
    a[8]=f2.x; a[9]=f2.y; a[10]=f2.z; a[11]=f2.w; a[12]=f3.x; a[13]=f3.y; a[14]=f3.z; a[15]=f3.w;
    float4 g0 = p1[0], g1 = p1[1], g2 = p1[2], g3 = p1[3];
    b[0]=g0.x; b[1]=g0.y; b[2]=g0.z; b[3]=g0.w; b[4]=g1.x; b[5]=g1.y; b[6]=g1.z; b[7]=g1.w;
    b[8]=g2.x; b[9]=g2.y; b[10]=g2.z; b[11]=g2.w; b[12]=g3.x; b[13]=g3.y; b[14]=g3.z; b[15]=g3.w;
  }
#pragma unroll
  for (int kh = 0; kh < 4; ++kh)
#pragma unroll
    for (int kw = 0; kw < 4; ++kw) {
      int r = (kh & 1) ? 0 : 1;
      int pp = (kw & 1) ? 0 : 1;
      int c = r * 2 + pp;
      int tap = (kh >> 1) * 2 + (kw >> 1);
      int ks = tap * 2 + ksq;
      unsigned u = (unsigned)f2bf(a[kh * 4 + kw] * A) |
                   ((unsigned)f2bf(b[kh * 4 + kw] * A) << 16);
      *(unsigned*)&g_wfrag[(((c * 8 + ks) * 4 + nt) * 64 + q * 16 + b15) * 8 + j] = u;
    }

  if (t < 64) {
    float Ai = gamma[t] * rsqrtf(var[t] + 1e-5f);
    g_aff[t] = (bias[t] - mean[t]) * Ai + beta[t];
  }
}

__global__ __launch_bounds__(256, 2) void fused_kernel(const float* __restrict__ x,
                                                       float* __restrict__ out) {
  __shared__ ushort xs[6 * COLS * 64];  // 50688 B halo (swizzled); reused as f32 red[2][64][66]

  const int tid  = threadIdx.x;
  const int ph0  = blockIdx.x * 4;  // first pooled row
  const int n    = blockIdx.y;
  const int wave = tid >> 6;        // = pooled row within block (wave owns full row)
  const int lane = tid & 63;
  const int b15  = lane & 15;
  const int q    = lane >> 4;

  // ---- stage x halo rows ph0-1..ph0+4, 64 cin bf16, swizzled [row][col][chunk^col&7] ----
  // lane <-> column; per iteration one (row,chunk): 8 strided dword loads (each
  // coalesced across lanes) -> one b128 write; swizzle spreads octets over 32 banks.
  {
    const int col = lane + 1;  // 1..64
#pragma unroll
    for (int i = 0; i < 12; ++i) {
      int pairidx = i * 4 + wave;  // 0..47
      int row = pairidx >> 3;      // 0..5
      int chunk = pairidx & 7;
      int ih = ph0 - 1 + row;
      float f[8] = {0.f, 0.f, 0.f, 0.f, 0.f, 0.f, 0.f, 0.f};
      if (ih >= 0 && ih < 64) {
        const float* xp = x + ((n * 64 + chunk * 8) * 64 + ih) * 64 + lane;
#pragma unroll
        for (int jj = 0; jj < 8; ++jj) f[jj] = xp[jj * 4096];
      }
      int4 pk;
      pk.x = (int)f2bf(f[0]) | ((int)f2bf(f[1]) << 16);
      pk.y = (int)f2bf(f[2]) | ((int)f2bf(f[3]) << 16);
      pk.z = (int)f2bf(f[4]) | ((int)f2bf(f[5]) << 16);
      pk.w = (int)f2bf(f[6]) | ((int)f2bf(f[7]) << 16);
      *(int4*)&xs[(row * COLS + col) * 64 + ((chunk ^ (col & 7)) * 8)] = pk;
    }
  }
  if (tid < 96) {  // zero-pad cols 0 and 65: 6 rows x 2 sides x 8 chunks
    int chunk = tid & 7, side = (tid >> 3) & 1, row = tid >> 4;
    int colp = side ? 65 : 0;
    int4 z = {0, 0, 0, 0};
    *(int4*)&xs[(row * COLS + colp) * 64 + ((chunk ^ (colp & 7)) * 8)] = z;
  }
  __syncthreads();

  float Dc[4];
#pragma unroll
  for (int nt = 0; nt < 4; ++nt) Dc[nt] = g_aff[nt * 16 + b15];

  // pooled as packed fp16: [mt*4+nt][pair] (pair 0 = regs 0,1; pair 1 = regs 2,3)
  h2 pooled[32];
#pragma unroll
  for (int i = 0; i < 32; ++i) pooled[i] = (h2){(_Float16)0.f, (_Float16)0.f};

  // bfrag double buffers; A holds ks=0 of the current class at each class entry
  short8 bfA[4], bfB[4];
  {
    const short8* wf = (const short8*)g_wfrag;  // class 0, ks 0
#pragma unroll
    for (int nt = 0; nt < 4; ++nt) bfA[nt] = wf[nt * 64 + lane];
  }

#pragma unroll
  for (int c = 0; c < 4; ++c) {
    const int r = c >> 1, p = c & 1;
    floatx4 acc[16];
#pragma unroll
    for (int i = 0; i < 16; ++i) acc[i] = (floatx4){0.f, 0.f, 0.f, 0.f};

#pragma unroll
    for (int ks = 0; ks < 8; ++ks) {
      short8* cur = (ks & 1) ? bfB : bfA;
      short8* nxt = (ks & 1) ? bfA : bfB;
      // ---- prefetch next bfrags (next ks, or next class's ks=0) ----
      if (ks < 7) {
        const short8* wf = (const short8*)g_wfrag + (c * 8 + ks + 1) * 256;
#pragma unroll
        for (int nt = 0; nt < 4; ++nt) nxt[nt] = wf[nt * 64 + lane];
      } else if (c < 3) {
        const short8* wf = (const short8*)g_wfrag + (c + 1) * 8 * 256;
#pragma unroll
        for (int nt = 0; nt < 4; ++nt) nxt[nt] = wf[nt * 64 + lane];
      }
      // ---- a-frags from LDS (4 m-tiles = 64 pw) ----
      const int a = ks >> 2, b = (ks >> 1) & 1;
      const int hrow = wave + (r ? (a ? 1 : 2) : (a ? 0 : 1));
      const int dx   = p ? (b ? 0 : 1) : (b ? -1 : 0);
      const int chunk = (ks & 1) * 4 + q;
      short8 af[4];
#pragma unroll
      for (int mt = 0; mt < 4; ++mt) {
        int col = mt * 16 + b15 + dx + 1;
        af[mt] = *(const short8*)&xs[(hrow * COLS + col) * 64 + ((chunk ^ (col & 7)) * 8)];
      }
      // ---- 16 MFMAs on current buffer (prefetch stays in flight) ----
#pragma unroll
      for (int nt = 0; nt < 4; ++nt)
#pragma unroll
        for (int mt = 0; mt < 4; ++mt)
          acc[mt * 4 + nt] =
              __builtin_amdgcn_mfma_f32_16x16x32_bf16(af[mt], cur[nt], acc[mt * 4 + nt], 0, 0, 0);
    }

    // BN-bias + softmax, exp in place (no max-subtraction: |logit| <~ 5; exp exact in f32)
#pragma unroll
    for (int mt = 0; mt < 4; ++mt) {
      float sm[4] = {0.f, 0.f, 0.f, 0.f};
#pragma unroll
      for (int nt = 0; nt < 4; ++nt)
#pragma unroll
        for (int reg = 0; reg < 4; ++reg) {
          float e = __expf(acc[mt * 4 + nt][reg] + Dc[nt]);
          acc[mt * 4 + nt][reg] = e;
          sm[reg] += e;
        }
#pragma unroll
      for (int reg = 0; reg < 4; ++reg) {
        sm[reg] += __shfl_xor(sm[reg], 1, 64);
        sm[reg] += __shfl_xor(sm[reg], 2, 64);
        sm[reg] += __shfl_xor(sm[reg], 4, 64);
        sm[reg] += __shfl_xor(sm[reg], 8, 64);
        sm[reg] = 1.0f / sm[reg];
      }
#pragma unroll
      for (int nt = 0; nt < 4; ++nt) {
        h2 p01 = {(_Float16)(acc[mt * 4 + nt][0] * sm[0]),
                  (_Float16)(acc[mt * 4 + nt][1] * sm[1])};
        h2 p23 = {(_Float16)(acc[mt * 4 + nt][2] * sm[2]),
                  (_Float16)(acc[mt * 4 + nt][3] * sm[3])};
        pooled[(mt * 4 + nt) * 2 + 0] = h2max(pooled[(mt * 4 + nt) * 2 + 0], p01);
        pooled[(mt * 4 + nt) * 2 + 1] = h2max(pooled[(mt * 4 + nt) * 2 + 1], p23);
      }
    }
  }

  // ---- output: 2 rows per pass transposed through LDS (overlaid), coalesced stores ----
  __syncthreads();  // halo reads complete in all waves
  float* red = (float*)xs;  // [2 rows][64 cout][66]
#pragma unroll
  for (int half = 0; half < 2; ++half) {
    if ((wave >> 1) == half) {
      int rl = wave & 1;
#pragma unroll
      for (int mt = 0; mt < 4; ++mt)
#pragma unroll
        for (int nt = 0; nt < 4; ++nt) {
          h2 lo = pooled[(mt * 4 + nt) * 2 + 0];
          h2 hi = pooled[(mt * 4 + nt) * 2 + 1];
          float* rp = &red[(rl * 64 + nt * 16 + b15) * 66 + mt * 16 + q * 4];
          rp[0] = (float)lo.x; rp[1] = (float)lo.y;
          rp[2] = (float)hi.x; rp[3] = (float)hi.y;
        }
    }
    __syncthreads();
    for (int e = tid; e < 4096; e += 256) {
      int pw2  = e & 31;
      int cout = (e >> 5) & 63;
      int rl   = e >> 11;
      float2 val = *(float2*)&red[(rl * 64 + cout) * 66 + pw2 * 2];
      *(float2*)&out[((n * 64 + cout) * 64 + (ph0 + half * 2 + rl)) * 64 + pw2 * 2] = val;
    }
    __syncthreads();  // before next pass overwrites red
  }
}

extern "C" void kernel_launch(void* const* d_in, const int* in_sizes, int n_in,
                              void* d_out, int out_size, void* d_ws, size_t ws_size,
                              hipStream_t stream) {
  const float* x     = (const float*)d_in[0];
  const float* w     = (const float*)d_in[1];
  const float* bias  = (const float*)d_in[2];
  const float* gamma = (const float*)d_in[3];
  const float* beta  = (const float*)d_in[4];
  const float* mean  = (const float*)d_in[5];
  const float* var   = (const float*)d_in[6];
  float* out = (float*)d_out;

  prep_kernel<<<8, 256, 0, stream>>>(w, bias, gamma, beta, mean, var);
  dim3 grid(16, 32);  // (4-row groups, n)
  fused_kernel<<<grid, 256, 0, stream>>>(x, out);
}

// Round 10
// 143.437 us; speedup vs baseline: 1.1520x; 1.1520x over previous
//
#include <hip/hip_runtime.h>
#include <math.h>

// Fused ConvTranspose2d(64->64,k4,s2,p1) + BN + softmax(C) + maxpool2x2 via bf16 MFMA.
//
// R10: CLASS-PER-WAVE. Block = 1 pooled row (ph,n); wave w <-> parity class w
//     (r=w>>1, p=w&1). Each wave: full row M=64 (4 m-tiles) x N=64 x K=256 for its
//     class -> acc[16] lives in AGPRs, each bfrag feeds 16 MFMAs, per-wave weight
//     read = 32 KB (256 MB total L2 traffic). Maxpool across classes via packed-h16
//     LDS pass (red4[4][64][33]) instead of registers -> no R8 spill.
//     exp via exp2: log2e folded into weights+bias at prep. Conflict-free staging
//     (R8b scheme, measured 0 conflicts). LDS 33792 -> 4 blocks/CU, grid 2048.

typedef __attribute__((ext_vector_type(8))) short short8;
typedef __attribute__((ext_vector_type(4))) float floatx4;
typedef _Float16 __attribute__((ext_vector_type(2))) h2;

#define COLS 66
#define LOG2E 1.44269504088896340736f

__device__ ushort g_wfrag[4 * 8 * 4 * 64 * 8];  // [class][ks][nt][lane][j], 128 KB
__device__ float g_aff[64];  // (D = (bias-mean)*A+beta) * log2e ; A*log2e folded into W

__device__ __forceinline__ ushort f2bf(float f) {
  union { float f; unsigned u; } v; v.f = f;
  unsigned r = v.u + 0x7FFF + ((v.u >> 16) & 1);  // RNE
  return (ushort)(r >> 16);
}

__device__ __forceinline__ h2 h2max(h2 a, h2 b) {
  h2 r;
  r.x = (a.x > b.x) ? a.x : b.x;
  r.y = (a.y > b.y) ? a.y : b.y;
  return r;
}

// prep: thread = (cin pair, cout). BN scale A and log2e folded into weights.
__global__ __launch_bounds__(256) void prep_kernel(
    const float* __restrict__ w, const float* __restrict__ bias,
    const float* __restrict__ gamma, const float* __restrict__ beta,
    const float* __restrict__ mean, const float* __restrict__ var) {
  int t = blockIdx.x * 256 + threadIdx.x;  // 0..2047
  int cin0 = (t >> 6) * 2;                 // even cin
  int cout = t & 63;
  int nt = cout >> 4, b15 = cout & 15;
  int q = (cin0 & 31) >> 3;                // quad within k-step
  int j = cin0 & 7;                        // j within quad (even)
  int ksq = cin0 >> 5;                     // which 32-block within tap
  float A = gamma[cout] * rsqrtf(var[cout] + 1e-5f) * LOG2E;

  const float4* p0 = (const float4*)&w[(cin0 * 64 + cout) * 16];
  const float4* p1 = (const float4*)&w[((cin0 + 1) * 64 + cout) * 16];
  float a[16], b[16];
  {
    float4 f0 = p0[0], f1 = p0[1], f2 = p0[2], f3 = p0[3];
    a[0]=f0.x; a[1]=f0.y; a[2]=f0.z; a[3]=f0.w; a[4]=f1.x; a[5]=f1.y; a[6]=f1.z; a[7]=f1.w;
    a[8]=f2.x; a[9]=f2.y; a[10]=f2.z; a[11]=f2.w; a[12]=f3.x; a[13]=f3.y; a[14]=f3.z; a[15]=f3.w;
    float4 g0 = p1[0], g1 = p1[1], g2 = p1[2], g3 = p1[3];
    b[0]=g0.x; b[1]=g0.y; b[2]=g0.z; b[3]=g0.w; b[4]=g1.x; b[5]=g1.y; b[6]=g1.z; b[7]=g1.w;
    b[8]=g2.x; b[9]=g2.y; b[10]=g2.z; b[11]=g2.w; b[12]=g3.x; b[13]=g3.y; b[14]=g3.z; b[15]=g3.w;
  }
#pragma unroll
  for (int kh = 0; kh < 4; ++kh)
#pragma unroll
    for (int kw = 0; kw < 4; ++kw) {
      int r = (kh & 1) ? 0 : 1;
      int pp = (kw & 1) ? 0 : 1;
      int c = r * 2 + pp;
      int tap = (kh >> 1) * 2 + (kw >> 1);
      int ks = tap * 2 + ksq;
      unsigned u = (unsigned)f2bf(a[kh * 4 + kw] * A) |
                   ((unsigned)f2bf(b[kh * 4 + kw] * A) << 16);
      *(unsigned*)&g_wfrag[(((c * 8 + ks) * 4 + nt) * 64 + q * 16 + b15) * 8 + j] = u;
    }

  if (t < 64) {
    float Ai = gamma[t] * rsqrtf(var[t] + 1e-5f);
    g_aff[t] = ((bias[t] - mean[t]) * Ai + beta[t]) * LOG2E;
  }
}

__global__ __launch_bounds__(256, 4) void fused_kernel(const float* __restrict__ x,
                                                       float* __restrict__ out) {
  // phase 1: halo rows ph-1..ph+1, [row][col 66][cin 64] bf16 swizzled = 25344 B
  // phase 2 (overlaid): red4 = h2[4 classes][64 cout][33 pw-pairs] = 33792 B
  __shared__ ushort xs[16896];

  const int tid  = threadIdx.x;
  const int ph   = blockIdx.x;  // pooled row
  const int n    = blockIdx.y;
  const int wave = tid >> 6;    // = parity class
  const int lane = tid & 63;
  const int b15  = lane & 15;
  const int q    = lane >> 4;

  // ---- stage halo (R8b conflict-free scheme): lane<->col, unit=(row,chunk) ----
  {
    const int col = lane + 1;  // 1..64
#pragma unroll
    for (int i = 0; i < 6; ++i) {
      int unit = i * 4 + wave;  // 0..23
      int row = unit >> 3;      // 0..2
      int chunk = unit & 7;
      int ih = ph - 1 + row;
      float f[8] = {0.f, 0.f, 0.f, 0.f, 0.f, 0.f, 0.f, 0.f};
      if (ih >= 0 && ih < 64) {
        const float* xp = x + ((n * 64 + chunk * 8) * 64 + ih) * 64 + lane;
#pragma unroll
        for (int jj = 0; jj < 8; ++jj) f[jj] = xp[jj * 4096];
      }
      int4 pk;
      pk.x = (int)f2bf(f[0]) | ((int)f2bf(f[1]) << 16);
      pk.y = (int)f2bf(f[2]) | ((int)f2bf(f[3]) << 16);
      pk.z = (int)f2bf(f[4]) | ((int)f2bf(f[5]) << 16);
      pk.w = (int)f2bf(f[6]) | ((int)f2bf(f[7]) << 16);
      *(int4*)&xs[(row * COLS + col) * 64 + ((chunk ^ (col & 7)) * 8)] = pk;
    }
  }
  if (tid < 48) {  // zero-pad cols 0 and 65: 3 rows x 2 sides x 8 chunks
    int chunk = tid & 7, side = (tid >> 3) & 1, row = tid >> 4;
    int colp = side ? 65 : 0;
    int4 z = {0, 0, 0, 0};
    *(int4*)&xs[(row * COLS + colp) * 64 + ((chunk ^ (colp & 7)) * 8)] = z;
  }
  __syncthreads();

  float Dc[4];
#pragma unroll
  for (int nt = 0; nt < 4; ++nt) Dc[nt] = g_aff[nt * 16 + b15];

  const int r = wave >> 1, p = wave & 1;  // this wave's class
  floatx4 acc[16];  // [mt*4+nt] -> AGPRs
#pragma unroll
  for (int i = 0; i < 16; ++i) acc[i] = (floatx4){0.f, 0.f, 0.f, 0.f};

#pragma unroll
  for (int ks = 0; ks < 8; ++ks) {
    const int a = ks >> 2, b = (ks >> 1) & 1;
    const int hrow = r ? (a ? 1 : 2) : (a ? 0 : 1);
    const int dx   = p ? (b ? 0 : 1) : (b ? -1 : 0);
    const int chunk = (ks & 1) * 4 + q;
    // B: 4 coalesced dwordx4 from L2 (this class only: 32 KB/wave total)
    const short8* wf = (const short8*)&g_wfrag[((wave * 8 + ks) * 4) * 512];
    short8 bf[4];
#pragma unroll
    for (int nt = 0; nt < 4; ++nt) bf[nt] = wf[nt * 64 + lane];
    // A: 4 swizzled b128 from LDS
    short8 af[4];
#pragma unroll
    for (int mt = 0; mt < 4; ++mt) {
      int col = mt * 16 + b15 + dx + 1;
      af[mt] = *(const short8*)&xs[(hrow * COLS + col) * 64 + ((chunk ^ (col & 7)) * 8)];
    }
    // 16 MFMAs per load set (~310 SIMD-cyc -> covers L2 latency w/ 4-wave TLP)
#pragma unroll
    for (int nt = 0; nt < 4; ++nt)
#pragma unroll
      for (int mt = 0; mt < 4; ++mt)
        acc[mt * 4 + nt] =
            __builtin_amdgcn_mfma_f32_16x16x32_bf16(af[mt], bf[nt], acc[mt * 4 + nt], 0, 0, 0);
  }

  // softmax per mt: exp2(acc + D') (log2e pre-folded); sum over 4 nt + 16 b15 lanes
  h2 res[32];  // [mt*8 + q... ] packed pw pairs; row pw = mt*16 + q*4 + reg
#pragma unroll
  for (int mt = 0; mt < 4; ++mt) {
    float sm[4] = {0.f, 0.f, 0.f, 0.f};
#pragma unroll
    for (int nt = 0; nt < 4; ++nt)
#pragma unroll
      for (int reg = 0; reg < 4; ++reg) {
        float e = exp2f(acc[mt * 4 + nt][reg] + Dc[nt]);
        acc[mt * 4 + nt][reg] = e;
        sm[reg] += e;
      }
#pragma unroll
    for (int reg = 0; reg < 4; ++reg) {
      sm[reg] += __shfl_xor(sm[reg], 1, 64);
      sm[reg] += __shfl_xor(sm[reg], 2, 64);
      sm[reg] += __shfl_xor(sm[reg], 4, 64);
      sm[reg] += __shfl_xor(sm[reg], 8, 64);
      sm[reg] = 1.0f / sm[reg];
    }
#pragma unroll
    for (int nt = 0; nt < 4; ++nt) {
      res[(mt * 4 + nt) * 2 + 0] = (h2){(_Float16)(acc[mt * 4 + nt][0] * sm[0]),
                                        (_Float16)(acc[mt * 4 + nt][1] * sm[1])};
      res[(mt * 4 + nt) * 2 + 1] = (h2){(_Float16)(acc[mt * 4 + nt][2] * sm[2]),
                                        (_Float16)(acc[mt * 4 + nt][3] * sm[3])};
    }
  }

  // ---- maxpool across classes via LDS: red4[class][cout][33 pw-pairs] (h2) ----
  __syncthreads();  // halo reads done everywhere; safe to overlay
  h2* red4 = (h2*)xs;
#pragma unroll
  for (int mt = 0; mt < 4; ++mt)
#pragma unroll
    for (int nt = 0; nt < 4; ++nt) {
      int cout = nt * 16 + b15;
      int pwp = mt * 8 + q * 2;
      red4[(wave * 64 + cout) * 33 + pwp + 0] = res[(mt * 4 + nt) * 2 + 0];
      red4[(wave * 64 + cout) * 33 + pwp + 1] = res[(mt * 4 + nt) * 2 + 1];
    }
  __syncthreads();
  for (int e = tid; e < 2048; e += 256) {
    int pwp  = e & 31;
    int cout = e >> 5;
    h2 v0 = red4[(0 * 64 + cout) * 33 + pwp];
    h2 v1 = red4[(1 * 64 + cout) * 33 + pwp];
    h2 v2 = red4[(2 * 64 + cout) * 33 + pwp];
    h2 v3 = red4[(3 * 64 + cout) * 33 + pwp];
    h2 mx = h2max(h2max(v0, v1), h2max(v2, v3));
    float2 val = {(float)mx.x, (float)mx.y};
    *(float2*)&out[((n * 64 + cout) * 64 + ph) * 64 + pwp * 2] = val;
  }
}

extern "C" void kernel_launch(void* const* d_in, const int* in_sizes, int n_in,
                              void* d_out, int out_size, void* d_ws, size_t ws_size,
                              hipStream_t stream) {
  const float* x     = (const float*)d_in[0];
  const float* w     = (const float*)d_in[1];
  const float* bias  = (const float*)d_in[2];
  const float* gamma = (const float*)d_in[3];
  const float* beta  = (const float*)d_in[4];
  const float* mean  = (const float*)d_in[5];
  const float* var   = (const float*)d_in[6];
  float* out = (float*)d_out;

  prep_kernel<<<8, 256, 0, stream>>>(w, bias, gamma, beta, mean, var);
  dim3 grid(64, 32);  // (ph, n)
  fused_kernel<<<grid, 256, 0, stream>>>(x, out);
}

// Round 12
// 120.868 us; speedup vs baseline: 1.3671x; 1.1867x over previous
//
#include <hip/hip_runtime.h>
#include <math.h>

// Fused ConvTranspose2d(64->64,k4,s2,p1) + BN + softmax(C) + maxpool2x2 via bf16 MFMA.
//
// R11: class-per-wave (R10) with the spill actually fixed:
//  - epilogue writes softmaxed h2 DIRECTLY to LDS red4 (res[32] deleted -> no scratch)
//  - __launch_bounds__(256,3): unified VGPR+AGPR cap ~170 (acc=64 AGPR + ~40 VGPR fits)
//  - XCD-aware ph swizzle: each XCD gets a contiguous 8-row band -> halo L2 reuse
// Block = 1 pooled row; wave w <-> parity class w; M=64 (4 mt) x N=64 x K=256.
// Weights in exact fragment order, 32 KB/class read straight from L2 (16 MFMAs/bfrag).

typedef __attribute__((ext_vector_type(8))) short short8;
typedef __attribute__((ext_vector_type(4))) float floatx4;
typedef _Float16 __attribute__((ext_vector_type(2))) h2;

#define COLS 66
#define LOG2E 1.44269504088896340736f

__device__ ushort g_wfrag[4 * 8 * 4 * 64 * 8];  // [class][ks][nt][lane][j], 128 KB
__device__ float g_aff[64];  // ((bias-mean)*A+beta) * log2e ; A*log2e folded into W

__device__ __forceinline__ ushort f2bf(float f) {
  union { float f; unsigned u; } v; v.f = f;
  unsigned r = v.u + 0x7FFF + ((v.u >> 16) & 1);  // RNE
  return (ushort)(r >> 16);
}

__device__ __forceinline__ h2 h2max(h2 a, h2 b) {
  h2 r;
  r.x = (a.x > b.x) ? a.x : b.x;
  r.y = (a.y > b.y) ? a.y : b.y;
  return r;
}

// prep: thread = (cin pair, cout). BN scale A and log2e folded into weights.
__global__ __launch_bounds__(256) void prep_kernel(
    const float* __restrict__ w, const float* __restrict__ bias,
    const float* __restrict__ gamma, const float* __restrict__ beta,
    const float* __restrict__ mean, const float* __restrict__ var) {
  int t = blockIdx.x * 256 + threadIdx.x;  // 0..2047
  int cin0 = (t >> 6) * 2;                 // even cin
  int cout = t & 63;
  int nt = cout >> 4, b15 = cout & 15;
  int q = (cin0 & 31) >> 3;                // quad within k-step
  int j = cin0 & 7;                        // j within quad (even)
  int ksq = cin0 >> 5;                     // which 32-block within tap
  float A = gamma[cout] * rsqrtf(var[cout] + 1e-5f) * LOG2E;

  const float4* p0 = (const float4*)&w[(cin0 * 64 + cout) * 16];
  const float4* p1 = (const float4*)&w[((cin0 + 1) * 64 + cout) * 16];
  float a[16], b[16];
  {
    float4 f0 = p0[0], f1 = p0[1], f2 = p0[2], f3 = p0[3];
    a[0]=f0.x; a[1]=f0.y; a[2]=f0.z; a[3]=f0.w; a[4]=f1.x; a[5]=f1.y; a[6]=f1.z; a[7]=f1.w;
    a[8]=f2.x; a[9]=f2.y; a[10]=f2.z; a[11]=f2.w; a[12]=f3.x; a[13]=f3.y; a[14]=f3.z; a[15]=f3.w;
    float4 g0 = p1[0], g1 = p1[1], g2 = p1[2], g3 = p1[3];
    b[0]=g0.x; b[1]=g0.y; b[2]=g0.z; b[3]=g0.w; b[4]=g1.x; b[5]=g1.y; b[6]=g1.z; b[7]=g1.w;
    b[8]=g2.x; b[9]=g2.y; b[10]=g2.z; b[11]=g2.w; b[12]=g3.x; b[13]=g3.y; b[14]=g3.z; b[15]=g3.w;
  }
#pragma unroll
  for (int kh = 0; kh < 4; ++kh)
#pragma unroll
    for (int kw = 0; kw < 4; ++kw) {
      int r = (kh & 1) ? 0 : 1;
      int pp = (kw & 1) ? 0 : 1;
      int c = r * 2 + pp;
      int tap = (kh >> 1) * 2 + (kw >> 1);
      int ks = tap * 2 + ksq;
      unsigned u = (unsigned)f2bf(a[kh * 4 + kw] * A) |
                   ((unsigned)f2bf(b[kh * 4 + kw] * A) << 16);
      *(unsigned*)&g_wfrag[(((c * 8 + ks) * 4 + nt) * 64 + q * 16 + b15) * 8 + j] = u;
    }

  if (t < 64) {
    float Ai = gamma[t] * rsqrtf(var[t] + 1e-5f);
    g_aff[t] = ((bias[t] - mean[t]) * Ai + beta[t]) * LOG2E;
  }
}

__global__ __launch_bounds__(256, 3) void fused_kernel(const float* __restrict__ x,
                                                       float* __restrict__ out) {
  // phase 1: halo rows ph-1..ph+1, [row][col 66][cin 64] bf16 swizzled = 25344 B
  // phase 2 (overlaid): red4 = h2[4 classes][64 cout][33 pw-pairs] = 33792 B
  __shared__ ushort xs[16896];

  const int tid  = threadIdx.x;
  const int bx   = blockIdx.x;
  const int ph   = ((bx & 7) << 3) | (bx >> 3);  // XCD-band swizzle: XCD k owns rows 8k..8k+7
  const int n    = blockIdx.y;
  const int wave = tid >> 6;    // = parity class
  const int lane = tid & 63;
  const int b15  = lane & 15;
  const int q    = lane >> 4;

  // ---- stage halo (conflict-free): lane<->col, unit=(row,chunk) ----
  {
    const int col = lane + 1;  // 1..64
#pragma unroll
    for (int i = 0; i < 6; ++i) {
      int unit = i * 4 + wave;  // 0..23
      int row = unit >> 3;      // 0..2
      int chunk = unit & 7;
      int ih = ph - 1 + row;
      float f[8] = {0.f, 0.f, 0.f, 0.f, 0.f, 0.f, 0.f, 0.f};
      if (ih >= 0 && ih < 64) {
        const float* xp = x + ((n * 64 + chunk * 8) * 64 + ih) * 64 + lane;
#pragma unroll
        for (int jj = 0; jj < 8; ++jj) f[jj] = xp[jj * 4096];
      }
      int4 pk;
      pk.x = (int)f2bf(f[0]) | ((int)f2bf(f[1]) << 16);
      pk.y = (int)f2bf(f[2]) | ((int)f2bf(f[3]) << 16);
      pk.z = (int)f2bf(f[4]) | ((int)f2bf(f[5]) << 16);
      pk.w = (int)f2bf(f[6]) | ((int)f2bf(f[7]) << 16);
      *(int4*)&xs[(row * COLS + col) * 64 + ((chunk ^ (col & 7)) * 8)] = pk;
    }
  }
  if (tid < 48) {  // zero-pad cols 0 and 65: 3 rows x 2 sides x 8 chunks
    int chunk = tid & 7, side = (tid >> 3) & 1, row = tid >> 4;
    int colp = side ? 65 : 0;
    int4 z = {0, 0, 0, 0};
    *(int4*)&xs[(row * COLS + colp) * 64 + ((chunk ^ (colp & 7)) * 8)] = z;
  }
  __syncthreads();

  float Dc[4];
#pragma unroll
  for (int nt = 0; nt < 4; ++nt) Dc[nt] = g_aff[nt * 16 + b15];

  const int r = wave >> 1, p = wave & 1;  // this wave's class
  floatx4 acc[16];  // [mt*4+nt] -> AGPRs (64 of the unified file)
#pragma unroll
  for (int i = 0; i < 16; ++i) acc[i] = (floatx4){0.f, 0.f, 0.f, 0.f};

#pragma unroll
  for (int ks = 0; ks < 8; ++ks) {
    const int a = ks >> 2, b = (ks >> 1) & 1;
    const int hrow = r ? (a ? 1 : 2) : (a ? 0 : 1);
    const int dx   = p ? (b ? 0 : 1) : (b ? -1 : 0);
    const int chunk = (ks & 1) * 4 + q;
    // B: 4 coalesced dwordx4 from L2 (this class only: 32 KB/wave total)
    const short8* wf = (const short8*)&g_wfrag[((wave * 8 + ks) * 4) * 512];
    short8 bf[4];
#pragma unroll
    for (int nt = 0; nt < 4; ++nt) bf[nt] = wf[nt * 64 + lane];
    // A: 4 swizzled b128 from LDS
    short8 af[4];
#pragma unroll
    for (int mt = 0; mt < 4; ++mt) {
      int col = mt * 16 + b15 + dx + 1;
      af[mt] = *(const short8*)&xs[(hrow * COLS + col) * 64 + ((chunk ^ (col & 7)) * 8)];
    }
    // 16 MFMAs per load set (covers L2 latency with 3-block TLP)
#pragma unroll
    for (int nt = 0; nt < 4; ++nt)
#pragma unroll
      for (int mt = 0; mt < 4; ++mt)
        acc[mt * 4 + nt] =
            __builtin_amdgcn_mfma_f32_16x16x32_bf16(af[mt], bf[nt], acc[mt * 4 + nt], 0, 0, 0);
  }

  // ---- softmax + write DIRECTLY to LDS red4 (no register staging buffer) ----
  __syncthreads();  // all halo reads done in every wave -> safe to overlay
  h2* red4 = (h2*)xs;  // [class][cout][33 pw-pairs]
#pragma unroll
  for (int mt = 0; mt < 4; ++mt) {
    float sm[4] = {0.f, 0.f, 0.f, 0.f};
#pragma unroll
    for (int nt = 0; nt < 4; ++nt)
#pragma unroll
      for (int reg = 0; reg < 4; ++reg) {
        float e = exp2f(acc[mt * 4 + nt][reg] + Dc[nt]);
        acc[mt * 4 + nt][reg] = e;
        sm[reg] += e;
      }
#pragma unroll
    for (int reg = 0; reg < 4; ++reg) {
      sm[reg] += __shfl_xor(sm[reg], 1, 64);
      sm[reg] += __shfl_xor(sm[reg], 2, 64);
      sm[reg] += __shfl_xor(sm[reg], 4, 64);
      sm[reg] += __shfl_xor(sm[reg], 8, 64);
      sm[reg] = 1.0f / sm[reg];
    }
#pragma unroll
    for (int nt = 0; nt < 4; ++nt) {
      int base = (wave * 64 + nt * 16 + b15) * 33 + mt * 8 + q * 2;
      red4[base + 0] = (h2){(_Float16)(acc[mt * 4 + nt][0] * sm[0]),
                            (_Float16)(acc[mt * 4 + nt][1] * sm[1])};
      red4[base + 1] = (h2){(_Float16)(acc[mt * 4 + nt][2] * sm[2]),
                            (_Float16)(acc[mt * 4 + nt][3] * sm[3])};
    }
  }
  __syncthreads();

  // ---- maxpool across classes + coalesced store ----
  for (int e = tid; e < 2048; e += 256) {
    int pwp  = e & 31;
    int cout = e >> 5;
    h2 v0 = red4[(0 * 64 + cout) * 33 + pwp];
    h2 v1 = red4[(1 * 64 + cout) * 33 + pwp];
    h2 v2 = red4[(2 * 64 + cout) * 33 + pwp];
    h2 v3 = red4[(3 * 64 + cout) * 33 + pwp];
    h2 mx = h2max(h2max(v0, v1), h2max(v2, v3));
    float2 val = {(float)mx.x, (float)mx.y};
    *(float2*)&out[((n * 64 + cout) * 64 + ph) * 64 + pwp * 2] = val;
  }
}

extern "C" void kernel_launch(void* const* d_in, const int* in_sizes, int n_in,
                              void* d_out, int out_size, void* d_ws, size_t ws_size,
                              hipStream_t stream) {
  const float* x     = (const float*)d_in[0];
  const float* w     = (const float*)d_in[1];
  const float* bias  = (const float*)d_in[2];
  const float* gamma = (const float*)d_in[3];
  const float* beta  = (const float*)d_in[4];
  const float* mean  = (const float*)d_in[5];
  const float* var   = (const float*)d_in[6];
  float* out = (float*)d_out;

  prep_kernel<<<8, 256, 0, stream>>>(w, bias, gamma, beta, mean, var);
  dim3 grid(64, 32);  // (ph-swizzled, n)
  fused_kernel<<<grid, 256, 0, stream>>>(x, out);
}